// Round 1
// baseline (617.502 us; speedup 1.0000x reference)
//
#include <hip/hip_runtime.h>
#include <stdint.h>

#define IN_F  4096
#define OUT_F 4096

typedef unsigned short u16;
typedef __attribute__((ext_vector_type(8))) short bf16x8;
typedef __attribute__((ext_vector_type(4))) float f32x4;

__device__ __forceinline__ u16 f2bf(float f) {
    union { float f; unsigned u; } c; c.f = f;
    unsigned u = c.u;
    return (u16)((u + 0x7FFFu + ((u >> 16) & 1u)) >> 16);
}
__device__ __forceinline__ float bf2f(u16 h) {
    union { unsigned u; float f; } c; c.u = ((unsigned)h) << 16;
    return c.f;
}

// async global->LDS, 16B per lane. LDS dest is wave-uniform base + lane*16.
__device__ __forceinline__ void load_lds16(const void* g, void* l) {
    unsigned loff = (unsigned)(uintptr_t)l;
    loff = (unsigned)__builtin_amdgcn_readfirstlane((int)loff);
    __builtin_amdgcn_global_load_lds(
        (const __attribute__((address_space(1))) void*)(uintptr_t)g,
        (__attribute__((address_space(3))) void*)(uintptr_t)loff,
        16, 0, 0);
}

// ---------------------------------------------------------------------------
// Kernel 1: dequant W[o][i] = lut[o][nibble(qw[i/8][o], i%8)]  -> bf16 [OUT][IN]
// one block per output row o; coalesced 16B writes; strided 4B qw reads (L2/LLC)
// ---------------------------------------------------------------------------
__global__ __launch_bounds__(256) void dequant_k(const int* __restrict__ qw,
                                                 const float* __restrict__ lut,
                                                 u16* __restrict__ W) {
    const int o = blockIdx.x;
    __shared__ u16 slut[16];
    if (threadIdx.x < 16) slut[threadIdx.x] = f2bf(lut[o * 16 + threadIdx.x]);
    __syncthreads();
#pragma unroll
    for (int it = 0; it < 2; ++it) {
        const int p = threadIdx.x + it * 256;          // packed word index, 0..511
        const unsigned w = (unsigned)qw[(size_t)p * OUT_F + o];
        union { u16 h[8]; uint4 v; } u;
#pragma unroll
        for (int j = 0; j < 8; ++j) u.h[j] = slut[(w >> (4 * j)) & 15u];
        *(uint4*)(W + (size_t)o * IN_F + (size_t)p * 8) = u.v;
    }
}

// ---------------------------------------------------------------------------
// Kernel 2: CSR outlier add. One thread per output row -> no atomics, and
// duplicate columns within a row accumulate serially like the reference.
// ---------------------------------------------------------------------------
__global__ __launch_bounds__(256) void outlier_k(u16* __restrict__ W,
                                                 const int* __restrict__ rows,
                                                 const int* __restrict__ cols,
                                                 const float* __restrict__ vals) {
    const int o = blockIdx.x * 256 + threadIdx.x;
    if (o >= OUT_F) return;
    const int s = rows[o], e = rows[o + 1];
    for (int k = s; k < e; ++k) {
        const int c = cols[k];
        const size_t idx = (size_t)o * IN_F + c;
        W[idx] = f2bf(bf2f(W[idx]) + vals[k]);
    }
}

// ---------------------------------------------------------------------------
// Kernel 3: x fp32 -> bf16 (RNE). 8 floats per thread, 16B stores.
// ---------------------------------------------------------------------------
__global__ __launch_bounds__(256) void cvtx_k(const float4* __restrict__ x,
                                              u16* __restrict__ xb) {
    const size_t i = (size_t)blockIdx.x * 256 + threadIdx.x;  // 8 floats each
    const float4 a = x[2 * i];
    const float4 b = x[2 * i + 1];
    union { u16 h[8]; uint4 v; } u;
    u.h[0] = f2bf(a.x); u.h[1] = f2bf(a.y); u.h[2] = f2bf(a.z); u.h[3] = f2bf(a.w);
    u.h[4] = f2bf(b.x); u.h[5] = f2bf(b.y); u.h[6] = f2bf(b.z); u.h[7] = f2bf(b.w);
    *(uint4*)(xb + i * 8) = u.v;
}

// ---------------------------------------------------------------------------
// Kernel 4: GEMM  y[M][N] = A[M][K] * B[N][K]^T + bias   (A,B bf16; y fp32)
// m97 structure: BM=BN=128, BK=32, 256 threads (4 waves, 2x2), each wave a
// 64x64 patch as 4x4 MFMA 16x16x32 tiles. global_load_lds 16B staging into
// unpadded [row][32] LDS tiles; 2-barrier K-loop.
// ---------------------------------------------------------------------------
#define BM 128
#define BN 128
#define BK 32
#define GK 4096

__global__ __launch_bounds__(256) void gemm_k(const u16* __restrict__ A,
                                              const u16* __restrict__ B,
                                              const float* __restrict__ bias,
                                              float* __restrict__ C,
                                              int M, int N) {
    __shared__ __align__(16) u16 sA[BM * BK];   // 8 KB
    __shared__ __align__(16) u16 sB[BN * BK];   // 8 KB

    const int tid  = threadIdx.x;
    const int wave = tid >> 6;
    const int lane = tid & 63;
    const int bm = blockIdx.y * BM;
    const int bn = blockIdx.x * BN;

    // staging: wave w covers 16 rows per instruction; lane l -> row w*16+l/4,
    // col (l%4)*8 elements. LDS dest = base + lane*16B (hardware).
    const int srow = wave * 16 + (lane >> 2);
    const int scol = (lane & 3) * 8;

    const u16* ga0 = A + (size_t)(bm + srow) * GK + scol;
    const u16* ga1 = ga0 + (size_t)64 * GK;
    const u16* gb0 = B + (size_t)(bn + srow) * GK + scol;
    const u16* gb1 = gb0 + (size_t)64 * GK;

    u16* la0 = sA + wave * 512;        // rows wave*16 .. +15
    u16* la1 = la0 + 2048;             // rows 64+wave*16 .. +15
    u16* lb0 = sB + wave * 512;
    u16* lb1 = lb0 + 2048;

    // fragment read: A[m=lane&15][k=(lane>>4)*8 + j]
    const int frow = lane & 15;
    const int fk   = (lane >> 4) * 8;

    const int wm = (wave >> 1) * 64;   // wave's patch inside the 128x128 tile
    const int wn = (wave & 1) * 64;

    f32x4 acc[4][4] = {};

    for (int k0 = 0; k0 < GK; k0 += BK) {
        __syncthreads();               // previous tile fully consumed
        load_lds16(ga0 + k0, la0);
        load_lds16(ga1 + k0, la1);
        load_lds16(gb0 + k0, lb0);
        load_lds16(gb1 + k0, lb1);
        __syncthreads();               // staging drained (vmcnt(0) before barrier)

        bf16x8 af[4], bfr[4];
#pragma unroll
        for (int t = 0; t < 4; ++t) {
            af[t]  = *(const bf16x8*)(sA + (wm + t * 16 + frow) * BK + fk);
            bfr[t] = *(const bf16x8*)(sB + (wn + t * 16 + frow) * BK + fk);
        }
#pragma unroll
        for (int i = 0; i < 4; ++i)
#pragma unroll
            for (int j = 0; j < 4; ++j)
                acc[i][j] = __builtin_amdgcn_mfma_f32_16x16x32_bf16(
                    af[i], bfr[j], acc[i][j], 0, 0, 0);
    }

    // epilogue: C/D layout col=lane&15, row=(lane>>4)*4+reg
    const int cm = bm + wm;
    const int cn = bn + wn;
#pragma unroll
    for (int j = 0; j < 4; ++j) {
        const int col = cn + j * 16 + (lane & 15);
        const float bv = bias[col];
#pragma unroll
        for (int i = 0; i < 4; ++i) {
            const int r0 = cm + i * 16 + (lane >> 4) * 4;
#pragma unroll
            for (int r = 0; r < 4; ++r)
                C[(size_t)(r0 + r) * N + col] = acc[i][j][r] + bv;
        }
    }
}

// ---------------------------------------------------------------------------
extern "C" void kernel_launch(void* const* d_in, const int* in_sizes, int n_in,
                              void* d_out, int out_size, void* d_ws, size_t ws_size,
                              hipStream_t stream) {
    (void)n_in; (void)out_size; (void)ws_size;
    const float* x     = (const float*)d_in[0];
    const float* lut   = (const float*)d_in[1];
    const float* bias  = (const float*)d_in[2];
    const float* ovals = (const float*)d_in[3];
    const int*   qw    = (const int*)d_in[4];
    const int*   orows = (const int*)d_in[5];
    const int*   ocols = (const int*)d_in[6];
    float* y = (float*)d_out;

    const int M = in_sizes[0] / IN_F;   // 8192

    u16* W  = (u16*)d_ws;                                        // 32 MB
    u16* xb = (u16*)((char*)d_ws + (size_t)OUT_F * IN_F * 2);    // 64 MB

    dequant_k<<<OUT_F, 256, 0, stream>>>(qw, lut, W);
    outlier_k<<<(OUT_F + 255) / 256, 256, 0, stream>>>(W, orows, ocols, ovals);
    cvtx_k<<<(size_t)M * IN_F / 8 / 256, 256, 0, stream>>>((const float4*)x, xb);
    dim3 grid(OUT_F / BN, M / BM);
    gemm_k<<<grid, 256, 0, stream>>>(xb, W, bias, y, M, OUT_F);
}

// Round 2
// 562.721 us; speedup vs baseline: 1.0973x; 1.0973x over previous
//
#include <hip/hip_runtime.h>
#include <stdint.h>

#define IN_F  4096
#define OUT_F 4096

typedef unsigned short u16;
typedef __attribute__((ext_vector_type(8))) short bf16x8;
typedef __attribute__((ext_vector_type(4))) float f32x4;

__device__ __forceinline__ u16 f2bf(float f) {
    union { float f; unsigned u; } c; c.f = f;
    unsigned u = c.u;
    return (u16)((u + 0x7FFFu + ((u >> 16) & 1u)) >> 16);
}
__device__ __forceinline__ float bf2f(u16 h) {
    union { unsigned u; float f; } c; c.u = ((unsigned)h) << 16;
    return c.f;
}

// async global->LDS, 16B per lane. LDS dest is wave-uniform base + lane*16.
__device__ __forceinline__ void load_lds16(const void* g, void* l) {
    unsigned loff = (unsigned)(uintptr_t)l;
    loff = (unsigned)__builtin_amdgcn_readfirstlane((int)loff);
    __builtin_amdgcn_global_load_lds(
        (const __attribute__((address_space(1))) void*)(uintptr_t)g,
        (__attribute__((address_space(3))) void*)(uintptr_t)loff,
        16, 0, 0);
}

// ---------------------------------------------------------------------------
// Kernel 1: fused dequant + CSR outliers -> W bf16 [OUT][IN]
// Block = 64 o-rows x 256 i-cols. LDS-tiled transpose:
//   read qw coalesced (o contiguous across lanes), LUT-decode into swizzled
//   LDS chunks (chunk ^ (row&31) -> bank-conflict-free both phases), apply
//   outliers per-row (single thread per row: duplicate cols stay serial),
//   write back 512B-contiguous rows.
// ---------------------------------------------------------------------------
#define DQ_O 64
#define DQ_I 256   // 32 packed words

__global__ __launch_bounds__(256) void dequant_k(const int* __restrict__ qw,
                                                 const float* __restrict__ lut,
                                                 const int* __restrict__ rows,
                                                 const int* __restrict__ cols,
                                                 const float* __restrict__ vals,
                                                 u16* __restrict__ W) {
    __shared__ __align__(16) u16 sW[DQ_O * DQ_I];   // 32 KB
    __shared__ u16 slut[DQ_O * 18];                 // padded stride 18 (9 dw, odd)

    const int tid = threadIdx.x;
    const int o0 = blockIdx.y * DQ_O;
    const int i0 = blockIdx.x * DQ_I;
    const int p0 = i0 >> 3;

    // stage LUT as bf16: 1024 entries, 4 per thread (aligned within a 16-row)
    {
        const int idx = tid * 4;
        const float4 v = *(const float4*)(lut + (size_t)o0 * 16 + idx);
        u16* d = slut + (idx >> 4) * 18 + (idx & 15);
        d[0] = f2bf(v.x); d[1] = f2bf(v.y); d[2] = f2bf(v.z); d[3] = f2bf(v.w);
    }
    __syncthreads();

    const int o_l = tid & 63;
    const int swz = o_l & 31;
#pragma unroll
    for (int it = 0; it < 8; ++it) {
        const int p = (tid >> 6) + it * 4;                       // 0..31
        const unsigned w = (unsigned)qw[(size_t)(p0 + p) * OUT_F + (o0 + o_l)];
        union { u16 h[8]; uint4 v; } u;
#pragma unroll
        for (int j = 0; j < 8; ++j)
            u.h[j] = slut[o_l * 18 + ((w >> (4 * j)) & 15u)];
        *(uint4*)(sW + o_l * DQ_I + ((p ^ swz) << 3)) = u.v;
    }
    __syncthreads();

    // CSR outliers: one thread per o-row, serial walk (reference semantics)
    if (tid < DQ_O) {
        const int s = rows[o0 + tid], e = rows[o0 + tid + 1];
        for (int k = s; k < e; ++k) {
            const unsigned j = (unsigned)(cols[k] - i0);
            if (j < DQ_I) {
                u16* p16 = sW + tid * DQ_I + (((j >> 3) ^ swz) << 3) + (j & 7);
                *p16 = f2bf(bf2f(*p16) + vals[k]);
            }
        }
    }
    __syncthreads();

    // writeback: 32 lanes x 16B = 512B contiguous per row
    const int ch = tid & 31;
#pragma unroll
    for (int it = 0; it < 8; ++it) {
        const int r = (tid >> 5) + it * 8;                       // 0..63
        *(uint4*)(W + (size_t)(o0 + r) * IN_F + i0 + ch * 8) =
            *(const uint4*)(sW + r * DQ_I + ((ch ^ (r & 31)) << 3));
    }
}

// ---------------------------------------------------------------------------
// Kernel 2: x fp32 -> bf16 (RNE). 8 floats per thread, 16B stores.
// ---------------------------------------------------------------------------
__global__ __launch_bounds__(256) void cvtx_k(const float4* __restrict__ x,
                                              u16* __restrict__ xb) {
    const size_t i = (size_t)blockIdx.x * 256 + threadIdx.x;
    const float4 a = x[2 * i];
    const float4 b = x[2 * i + 1];
    union { u16 h[8]; uint4 v; } u;
    u.h[0] = f2bf(a.x); u.h[1] = f2bf(a.y); u.h[2] = f2bf(a.z); u.h[3] = f2bf(a.w);
    u.h[4] = f2bf(b.x); u.h[5] = f2bf(b.y); u.h[6] = f2bf(b.z); u.h[7] = f2bf(b.w);
    *(uint4*)(xb + i * 8) = u.v;
}

// ---------------------------------------------------------------------------
// Kernel 3: GEMM  y[M][N] = A[M][K] * B[N][K]^T + bias   (A,B bf16; y fp32)
// m97 structure: BM=BN=128, BK=32, 4 waves, 4x4 16x16x32 MFMA per wave,
// global_load_lds 16B staging, 2-barrier K-loop.
// ---------------------------------------------------------------------------
#define BM 128
#define BN 128
#define BK 32
#define GK 4096

__global__ __launch_bounds__(256) void gemm_k(const u16* __restrict__ A,
                                              const u16* __restrict__ B,
                                              const float* __restrict__ bias,
                                              float* __restrict__ C,
                                              int M, int N) {
    __shared__ __align__(16) u16 sA[BM * BK];
    __shared__ __align__(16) u16 sB[BN * BK];

    const int tid  = threadIdx.x;
    const int wave = tid >> 6;
    const int lane = tid & 63;
    const int bm = blockIdx.y * BM;
    const int bn = blockIdx.x * BN;

    const int srow = wave * 16 + (lane >> 2);
    const int scol = (lane & 3) * 8;

    const u16* ga0 = A + (size_t)(bm + srow) * GK + scol;
    const u16* ga1 = ga0 + (size_t)64 * GK;
    const u16* gb0 = B + (size_t)(bn + srow) * GK + scol;
    const u16* gb1 = gb0 + (size_t)64 * GK;

    u16* la0 = sA + wave * 512;
    u16* la1 = la0 + 2048;
    u16* lb0 = sB + wave * 512;
    u16* lb1 = lb0 + 2048;

    const int frow = lane & 15;
    const int fk   = (lane >> 4) * 8;

    const int wm = (wave >> 1) * 64;
    const int wn = (wave & 1) * 64;

    f32x4 acc[4][4] = {};

    for (int k0 = 0; k0 < GK; k0 += BK) {
        __syncthreads();
        load_lds16(ga0 + k0, la0);
        load_lds16(ga1 + k0, la1);
        load_lds16(gb0 + k0, lb0);
        load_lds16(gb1 + k0, lb1);
        __syncthreads();

        bf16x8 af[4], bfr[4];
#pragma unroll
        for (int t = 0; t < 4; ++t) {
            af[t]  = *(const bf16x8*)(sA + (wm + t * 16 + frow) * BK + fk);
            bfr[t] = *(const bf16x8*)(sB + (wn + t * 16 + frow) * BK + fk);
        }
#pragma unroll
        for (int i = 0; i < 4; ++i)
#pragma unroll
            for (int j = 0; j < 4; ++j)
                acc[i][j] = __builtin_amdgcn_mfma_f32_16x16x32_bf16(
                    af[i], bfr[j], acc[i][j], 0, 0, 0);
    }

    const int cm = bm + wm;
    const int cn = bn + wn;
#pragma unroll
    for (int j = 0; j < 4; ++j) {
        const int col = cn + j * 16 + (lane & 15);
        const float bv = bias[col];
#pragma unroll
        for (int i = 0; i < 4; ++i) {
            const int r0 = cm + i * 16 + (lane >> 4) * 4;
#pragma unroll
            for (int r = 0; r < 4; ++r)
                C[(size_t)(r0 + r) * N + col] = acc[i][j][r] + bv;
        }
    }
}

// ---------------------------------------------------------------------------
extern "C" void kernel_launch(void* const* d_in, const int* in_sizes, int n_in,
                              void* d_out, int out_size, void* d_ws, size_t ws_size,
                              hipStream_t stream) {
    (void)n_in; (void)out_size; (void)ws_size;
    const float* x     = (const float*)d_in[0];
    const float* lut   = (const float*)d_in[1];
    const float* bias  = (const float*)d_in[2];
    const float* ovals = (const float*)d_in[3];
    const int*   qw    = (const int*)d_in[4];
    const int*   orows = (const int*)d_in[5];
    const int*   ocols = (const int*)d_in[6];
    float* y = (float*)d_out;

    const int M = in_sizes[0] / IN_F;   // 8192

    u16* W  = (u16*)d_ws;                                        // 32 MB
    u16* xb = (u16*)((char*)d_ws + (size_t)OUT_F * IN_F * 2);    // 64 MB

    dim3 dq_grid(IN_F / DQ_I, OUT_F / DQ_O);
    dequant_k<<<dq_grid, 256, 0, stream>>>(qw, lut, orows, ocols, ovals, W);
    cvtx_k<<<(size_t)M * IN_F / 8 / 256, 256, 0, stream>>>((const float4*)x, xb);
    dim3 grid(OUT_F / BN, M / BM);
    gemm_k<<<grid, 256, 0, stream>>>(xb, W, bias, y, M, OUT_F);
}